// Round 3
// baseline (124.132 us; speedup 1.0000x reference)
//
#include <hip/hip_runtime.h>
#include <math.h>

#define N_FRAMES 20000
#define N_BEADS  50
#define N_DIST   1225   // sum_{inc=1}^{49} (50-inc)
#define N_ANG    48
#define N_DIH    47
#define OUT_STRIDE (N_DIST + N_ANG + 2 * N_DIH)  // 1367 floats = 5468 B (== 12 mod 16!)
#define FPB      8              // frames per block; 20000/8 = 2500 blocks
#define HALF     4              // output staged+copied 4 frames at a time
#define FRAME_F  (N_BEADS * 3)  // 150 packed floats per frame (global)
#define FRAME_P  (N_BEADS * 4)  // 200 padded floats per frame (LDS, float4/bead)

// cumulative pair count before separation `inc`:
// cum(inc) = sum_{k=1}^{inc-1} (50-k) = (inc-1)*50 - (inc-1)*inc/2
__device__ __forceinline__ int cum_pairs(int inc) {
    return (inc - 1) * 50 - ((inc - 1) * inc) / 2;
}

// Fast HW approx ops (single instruction, ~1 ulp rel err ~2^-22).
__device__ __forceinline__ float fsqrt_fast(float x) { return __builtin_amdgcn_sqrtf(x); }
__device__ __forceinline__ float frsq_fast(float x)  { return __builtin_amdgcn_rsqf(x); }

// R3 structure: compute -> LDS staging -> bulk aligned copy-out.
// Why: R0-R2 showed no pipe >30% busy yet kernel ~58us. Remaining suspect:
// 44 scattered global_store_dword/thread force store-data register reuse
// -> vmcnt waits on L2 store acks inside the compute loops, and the
// 1367-float row stride (== 12 mod 16 B) forbids dwordx4 stores per row.
// Per-BLOCK output (8 rows = 43744 B) IS contiguous and 16B-aligned, so:
// stage 4-frame halves in LDS (21.9 KB, reused), then stream out as
// ds_read_b128 -> global_store_dwordx4 (1 KB/wave-instr, fill-like).
// LDS total ~28.3 KB -> 5 blocks/CU -> 20 waves/CU (TLP regime unchanged;
// R1/R2 proved TLP beyond ~16 waves is not the constraint).
__global__ __launch_bounds__(256, 5)
void protein_feat_kernel(const float* __restrict__ data, float* __restrict__ out) {
    const int tid = threadIdx.x;
    const int f0  = blockIdx.x * FPB;

    __shared__ __align__(16) float s[FPB * FRAME_P];        // 6.4 KB input, float4/bead
    __shared__ __align__(16) float sout[HALF * OUT_STRIDE]; // 21.9 KB staged output

    // ---- stage input: issue global loads first, overlap index math ----
    const float4* g4 = (const float4*)(data + (size_t)f0 * FRAME_F);
    float4 v0 = g4[tid];                      // 300 float4s total; tid<256 always valid
    const bool h2 = (tid + 256) < (FPB * FRAME_F / 4);
    float4 v1;
    if (h2) v1 = g4[tid + 256];

    // frame-independent pair bead-indices (overlaps the vmem latency)
    int bi_idx[5], bj_idx[5];
#pragma unroll
    for (int k = 0; k < 5; ++k) {
        int p = tid + k * 256;
        if (p < N_DIST) {
            float disc = 9801.0f - 8.0f * (float)p;
            int inc = (int)((101.0f - sqrtf(disc)) * 0.5f);
            inc = min(max(inc, 1), 49);
            while (inc < 49 && cum_pairs(inc + 1) <= p) ++inc;  // float-rounding fixup
            while (inc > 1  && cum_pairs(inc)     >  p) --inc;
            int i = p - cum_pairs(inc);
            bi_idx[k] = i;
            bj_idx[k] = i + inc;
        } else {
            bi_idx[k] = 0; bj_idx[k] = 0;
        }
    }
    const bool has_tail = (1024 + tid) < N_DIST;  // tid < 201

    // repack packed(xyz) -> padded(float4/bead) into LDS
    {
        int gi = 4 * tid;
#pragma unroll
        for (int c = 0; c < 4; ++c) {
            int B  = (gi + c) / 3;
            int cc = (gi + c) - 3 * B;
            s[B * 4 + cc] = (&v0.x)[c];
        }
        if (h2) {
            int gj = 4 * (tid + 256);
#pragma unroll
            for (int c = 0; c < 4; ++c) {
                int B  = (gj + c) / 3;
                int cc = (gj + c) - 3 * B;
                s[B * 4 + cc] = (&v1.x)[c];
            }
        }
    }
    __syncthreads();

#pragma unroll 1
    for (int half = 0; half < 2; ++half) {
        const int fbase = half * HALF;  // first frame of this half (block-local)

        // ---- distances: 4 frames, 5 pairs/thread, writes to LDS ----
#pragma unroll 1
        for (int fl = 0; fl < HALF; ++fl) {
            const float4* sf4 = (const float4*)s + (fbase + fl) * N_BEADS;
            float* fo = sout + fl * OUT_STRIDE;
#pragma unroll
            for (int k = 0; k < 4; ++k) {   // p = tid + k*256 < 1024 always valid
                float4 bi = sf4[bi_idx[k]];
                float4 bj = sf4[bj_idx[k]];
                float dx = bj.x - bi.x;
                float dy = bj.y - bi.y;
                float dz = bj.z - bi.z;
                fo[tid + k * 256] = fsqrt_fast(dx * dx + dy * dy + dz * dz);
            }
            if (has_tail) {
                float4 bi = sf4[bi_idx[4]];
                float4 bj = sf4[bj_idx[4]];
                float dx = bj.x - bi.x;
                float dy = bj.y - bi.y;
                float dz = bj.z - bi.z;
                fo[tid + 1024] = fsqrt_fast(dx * dx + dy * dy + dz * dz);
            }
        }

        // ---- angles: 4 frames x 48 = 192 items (single pass, tid < 192) ----
        if (tid < HALF * N_ANG) {
            int fl = tid / N_ANG;
            int a  = tid - fl * N_ANG;
            const float4* sf4 = (const float4*)s + (fbase + fl) * N_BEADS;
            float4 A = sf4[a], B = sf4[a + 1], C = sf4[a + 2];
            float b1x = A.x - B.x, b1y = A.y - B.y, b1z = A.z - B.z;
            float b2x = C.x - B.x, b2y = C.y - B.y, b2z = C.z - B.z;
            float dot = b1x * b2x + b1y * b2y + b1z * b2z;
            float s1 = b1x * b1x + b1y * b1y + b1z * b1z;
            float s2 = b2x * b2x + b2y * b2y + b2z * b2z;
            float c = dot * frsq_fast(s1 * s2);
            c = fminf(1.0f, fmaxf(-1.0f, c));
            sout[fl * OUT_STRIDE + N_DIST + a] = acosf(c);
        }

        // ---- dihedrals: 4 frames x 47 = 188 items (single pass, tid < 188) ----
        if (tid < HALF * N_DIH) {
            int fl = tid / N_DIH;
            int d  = tid - fl * N_DIH;
            const float4* sf4 = (const float4*)s + (fbase + fl) * N_BEADS;
            float4 P0 = sf4[d], P1 = sf4[d + 1], P2 = sf4[d + 2], P3 = sf4[d + 3];

            float ax = P1.x - P0.x, ay = P1.y - P0.y, az = P1.z - P0.z;
            float bx = P2.x - P1.x, by = P2.y - P1.y, bz = P2.z - P1.z;
            float cx = P3.x - P2.x, cy = P3.y - P2.y, cz = P3.z - P2.z;

            float p1x = ay * bz - az * by;
            float p1y = az * bx - ax * bz;
            float p1z = ax * by - ay * bx;
            float p2x = by * cz - bz * cy;
            float p2y = bz * cx - bx * cz;
            float p2z = bx * cy - by * cx;

            float s1 = p1x * p1x + p1y * p1y + p1z * p1z;
            float s2 = p2x * p2x + p2y * p2y + p2z * p2z;
            float sb = bx * bx + by * by + bz * bz;

            float dotp = p1x * p2x + p1y * p2y + p1z * p2z;
            float qx = p1y * p2z - p1z * p2y;
            float qy = p1z * p2x - p1x * p2z;
            float qz = p1x * p2y - p1y * p2x;
            float trip = qx * bx + qy * by + qz * bz;

            float inv12 = frsq_fast(s1 * s2);
            float invb  = frsq_fast(sb);
            float* base = sout + fl * OUT_STRIDE + N_DIST + N_ANG;
            base[d]         = dotp * inv12;
            base[N_DIH + d] = trip * inv12 * invb;
        }

        __syncthreads();  // sout fully written

        // ---- bulk copy-out: 4 rows = 21872 B, contiguous & 16B-aligned ----
        // dst byte offset = (f0 + half*4)*5468 = blk*43744 + half*21872, both /16.
        {
            const float4* src4 = (const float4*)sout;
            float4* dst4 = (float4*)(out + (size_t)(f0 + fbase) * OUT_STRIDE);
#pragma unroll 1
            for (int x = tid; x < HALF * OUT_STRIDE / 4; x += 256) {  // 1367 float4s
                dst4[x] = src4[x];
            }
        }

        __syncthreads();  // protect sout before half 1 overwrites it
    }
}

extern "C" void kernel_launch(void* const* d_in, const int* in_sizes, int n_in,
                              void* d_out, int out_size, void* d_ws, size_t ws_size,
                              hipStream_t stream) {
    const float* data = (const float*)d_in[0];
    float* out = (float*)d_out;
    protein_feat_kernel<<<N_FRAMES / FPB, 256, 0, stream>>>(data, out);
}